// Round 8
// baseline (2443.809 us; speedup 1.0000x reference)
//
#include <hip/hip_runtime.h>
#include <hip/hip_bf16.h>
#include <cstdint>
#include <cstddef>

// ---------------------------------------------------------------------------
// VQ-VAE forward (B=2048, L=100, D=64, K=64, CB=512) — batched-M GEMM v4.
// Every conv = im2col GEMM, M = B*NPOS (BM=128, exact multiple: M=128*16*NPOS
// /128 -> no padding, no bounds checks). Tap shift baked into the STAGING
// address; LDS rows == output rows (no arow tables / zero row).
// Grid remap: all N-slices of an M-tile land on one XCD (wg&7 = mt%8).
// Encoder: split-bf16 (hi+lo, 3 MFMAs) ~f32; decoder: plain bf16.
// Activations: packed u32 (hi|lo) encoder, bf16 decoder. Argmin exactness:
// margin 0.1 flag -> f64 full recompute of flagged rows.
// ---------------------------------------------------------------------------

typedef __attribute__((ext_vector_type(8))) short short8v;   // 8 bf16
typedef __attribute__((ext_vector_type(4))) float f32x4;

constexpr int B  = 2048;
constexpr int L  = 100;
constexpr int K  = 64;
constexpr int CB = 512;
#define MARGIN 0.1f

// ---- workspace layout (float-sized units) ----
constexpr size_t R0_OFF  = 0;          // A1P u32 -> XE f32 -> G2 bf16
constexpr size_t R1_OFF  = 51380224;   // A2P u32 -> G1 bf16
constexpr size_t IDX_OFF = 84934656;   // 2048*49 ints
constexpr size_t UBT_OFF = 85035008;   // 512*64 f32 transposed codebook
constexpr size_t CBN_OFF = 85067776;   // 64 norms
constexpr size_t CNT_OFF = 85067840;
constexpr size_t ACC_OFF = 85067856;
constexpr size_t WL_OFF  = 85067872;   // 100352 ints
constexpr size_t WB_OFF  = 85168224;   // bf16 weights (ushort units below)

// bf16 weight sub-offsets (ushort units), layout [4][OC][IC]
constexpr size_t EW1H=0,       EW1L=32768;
constexpr size_t EW2H=65536,   EW2L=196608;
constexpr size_t EW3H=327680,  EW3L=851968;
constexpr size_t DW1H=1376256, DW2H=1900544, DW3H=2031616;
constexpr size_t BKB =2064384;  // book bf16 [64][512]

__device__ inline ushort bf16_hi(float f){ __hip_bfloat16 h=__float2bfloat16(f); return *(ushort*)&h; }
__device__ inline float  bf16_tof(ushort u){ __hip_bfloat16 h; *(ushort*)&h=u; return __bfloat162float(h); }

// ---------------------------------------------------------------------------
// weight prep: w[2,2,IC,OC] f32 -> Wt[kk][oc][ic] bf16 hi (+lo for encoder);
// book -> bf16.
// ---------------------------------------------------------------------------
__device__ void wtrans(const float* __restrict__ w, int IC, int OC,
                       ushort* __restrict__ hi, ushort* __restrict__ lo,
                       int gid, int gsz)
{
    int tot = 4*IC*OC;
    for (int i = gid; i < tot; i += gsz) {
        int kk = i/(IC*OC), r = i - kk*(IC*OC), ic = r/OC, oc = r - ic*OC;
        float v = w[i];
        ushort h = bf16_hi(v);
        size_t dst = ((size_t)kk*OC + oc)*IC + ic;
        hi[dst] = h;
        if (lo) lo[dst] = bf16_hi(v - bf16_tof(h));
    }
}

__global__ __launch_bounds__(256)
void wprep_k(const float* e1, const float* e2, const float* e3,
             const float* d1, const float* d2, const float* d3,
             const float* book, ushort* wb)
{
    int gid = blockIdx.x*256 + threadIdx.x, gsz = gridDim.x*256;
    wtrans(e1,  64, 128, wb+EW1H, wb+EW1L, gid, gsz);
    wtrans(e2, 128, 256, wb+EW2H, wb+EW2L, gid, gsz);
    wtrans(e3, 256, 512, wb+EW3H, wb+EW3L, gid, gsz);
    wtrans(d1, 512, 256, wb+DW1H, nullptr, gid, gsz);
    wtrans(d2, 256, 128, wb+DW2H, nullptr, gid, gsz);
    wtrans(d3, 128,  64, wb+DW3H, nullptr, gid, gsz);
    for (int i = gid; i < 64*512; i += gsz) wb[BKB+i] = bf16_hi(book[i]);
}

// ---------------------------------------------------------------------------
// Batched-M im2col GEMM conv. Block = (m-tile of 128 rows, n-slice).
// Grid remap: mt = 8*(i/NS) + (wg&7), ns = i%NS  -> all slices of an m-tile
// on one XCD. 4 waves in 2x2; per-wave 64 x BN/2 output (MT=4, NT=BN/32).
// Per chunk (tap kk, 64-ic block): stage 128 rows at tap offset into LDS
// (XOR-swizzled), T14: next chunk's global loads issue before current MFMAs.
// MODE 1: table gather+mask (f32->hi/lo); 2: book bf16 via qidx;
// 3: packed u32 hi|lo; 4: bf16.  OUTFMT 0: f32; 1: packed u32; 2: bf16.
// ---------------------------------------------------------------------------
template<int IH,int IW,int IC,int OC,int PAD,int MODE,bool HASBN,bool SPLIT,
         int NS,int BN,int OUTFMT>
__global__ __launch_bounds__(256)
void bconv_k(const uint* __restrict__ in_pk, const ushort* __restrict__ in_bf,
             const int* __restrict__ ids, const int* __restrict__ masks,
             const float* __restrict__ table,
             const int* __restrict__ qidx, const ushort* __restrict__ bookbf,
             const ushort* __restrict__ wt_hi, const ushort* __restrict__ wt_lo,
             const float* __restrict__ bias, const float* __restrict__ gamma,
             const float* __restrict__ beta,
             float* __restrict__ out_f, uint* __restrict__ out_pk,
             ushort* __restrict__ out_bf)
{
    constexpr int OH=IH+2*PAD-1, OW=IW+2*PAD-1, NPOS=OH*OW, IHW=IH*IW;
    constexpr int BM=128, RB=128;            // rows/block, LDS row bytes
    constexpr int MT=4, NT=BN/32;            // per-wave 64 x BN/2
    constexpr int ICN=IC/64, NCHT=4*ICN;     // chunks: tap-major, 64-ic blocks
    constexpr int PL=SPLIT?2:1;
    constexpr int SI=4;                      // 128 rows * 8 slots / 256 thr

    __shared__ ushort s_a[PL*BM*64];
    char* sb=(char*)s_a;

    // XCD-aware remap
    const int wg=blockIdx.x, r8=wg&7, i=wg>>3;
    const int mt = 8*(i/NS) + r8;
    const int ns = i - (i/NS)*NS;
    const int m0 = mt*BM;

    const int tid=threadIdx.x, lane=tid&63, wv=tid>>6;
    const int wr=wv>>1, wc=wv&1;
    const int l15=lane&15, lq=lane>>4, l7=l15&7;
    const int n0 = ns*BN + wc*(BN/2);
    const int rowt = tid>>3, slot = tid&7;   // staging geometry (stride 32 rows)

    f32x4 acc[MT][NT];
    #pragma unroll
    for(int m=0;m<MT;++m)
        #pragma unroll
        for(int n=0;n<NT;++n) acc[m][n]=(f32x4)0.0f;

    uint4 r0[SI];
    uint4 r1[(MODE==1||MODE==3)?SI:1];
    float msk[(MODE==1)?SI:1];
    const uint4 z4=make_uint4(0,0,0,0);

    auto stage_load=[&](int c){
        const int kk=c/ICN, icb=c-kk*ICN, ic0=icb*64;
        const int ky=kk>>1, kx=kk&1;
        #pragma unroll
        for(int t=0;t<SI;++t){
            int row=rowt+t*32;
            int g=m0+row;
            int b=g/NPOS, p=g-b*NPOS;
            int py=p/OW, px=p-py*OW;
            int iy=py+ky-PAD, ix=px+kx-PAD;
            bool ok = (PAD==0) || (((unsigned)iy<(unsigned)IH)&&((unsigned)ix<(unsigned)IW));
            int cell = ok ? iy*IW+ix : 0;
            if constexpr(MODE==1){
                int id=ids[b*L+cell];
                msk[t]=(masks[b*L+cell]>=1)?1.f:0.f;
                const float* src=table+(size_t)id*64+slot*8;
                r0[t]=*(const uint4*)src;
                r1[t]=*(const uint4*)(src+4);
            } else if constexpr(MODE==2){
                int kq=qidx[b*49+cell];
                r0[t]= ok ? *(const uint4*)(bookbf+(size_t)kq*512+ic0+slot*8) : z4;
            } else if constexpr(MODE==3){
                const uint* src=in_pk+((size_t)b*IHW+cell)*IC+ic0+slot*8;
                r0[t]= ok ? *(const uint4*)src : z4;
                r1[t]= ok ? *(const uint4*)(src+4) : z4;
            } else {
                r0[t]= ok ? *(const uint4*)(in_bf+((size_t)b*IHW+cell)*IC+ic0+slot*8) : z4;
            }
        }
    };

    auto stage_write=[&](){
        #pragma unroll
        for(int t=0;t<SI;++t){
            int row=rowt+t*32;
            int boff=row*RB+((slot^(row&7))<<4);
            if constexpr(MODE==1){
                const float* f0=(const float*)&r0[t];
                const float* f1=(const float*)&r1[t];
                float vv[8]={f0[0]*msk[t],f0[1]*msk[t],f0[2]*msk[t],f0[3]*msk[t],
                             f1[0]*msk[t],f1[1]*msk[t],f1[2]*msk[t],f1[3]*msk[t]};
                ushort hh[8], ll[8];
                #pragma unroll
                for(int j=0;j<8;++j){ hh[j]=bf16_hi(vv[j]); ll[j]=bf16_hi(vv[j]-bf16_tof(hh[j])); }
                *(uint4*)(sb+boff)=*(uint4*)hh;
                *(uint4*)(sb+BM*RB+boff)=*(uint4*)ll;
            } else if constexpr(MODE==3){
                const uint* u0=(const uint*)&r0[t];
                const uint* u1=(const uint*)&r1[t];
                ushort hh[8], ll[8];
                #pragma unroll
                for(int j=0;j<4;++j){ hh[j]=(ushort)(u0[j]&0xffffu); ll[j]=(ushort)(u0[j]>>16); }
                #pragma unroll
                for(int j=0;j<4;++j){ hh[4+j]=(ushort)(u1[j]&0xffffu); ll[4+j]=(ushort)(u1[j]>>16); }
                *(uint4*)(sb+boff)=*(uint4*)hh;
                *(uint4*)(sb+BM*RB+boff)=*(uint4*)ll;
            } else {
                *(uint4*)(sb+boff)=r0[t];
            }
        }
    };

    stage_load(0);
    for(int c=0;c<NCHT;++c){
        if(c) __syncthreads();          // previous MFMAs done reading LDS
        stage_write();
        __syncthreads();
        if(c+1<NCHT) stage_load(c+1);   // T14: next chunk's loads in flight
        const int kk=c/ICN, icb=c-kk*ICN, ic0=icb*64;
        #pragma unroll
        for(int ks=0;ks<2;++ks){
            short8v bhv[NT]; short8v blv[SPLIT?NT:1];
            #pragma unroll
            for(int n=0;n<NT;++n){
                int col=n0+n*16+l15;
                size_t widx=((size_t)kk*OC+col)*IC+ic0+ks*32+lq*8;
                bhv[n]=*(const short8v*)(wt_hi+widx);
                if constexpr(SPLIT) blv[n]=*(const short8v*)(wt_lo+widx);
            }
            #pragma unroll
            for(int m=0;m<MT;++m){
                int rl=wr*64+m*16+l15;
                int off=rl*RB + ((((ks<<2)|lq)^l7)<<4);
                short8v ah=*(const short8v*)(sb+off);
                if constexpr(SPLIT){
                    short8v al=*(const short8v*)(sb+BM*RB+off);
                    #pragma unroll
                    for(int n=0;n<NT;++n){
                        acc[m][n]=__builtin_amdgcn_mfma_f32_16x16x32_bf16(ah,bhv[n],acc[m][n],0,0,0);
                        acc[m][n]=__builtin_amdgcn_mfma_f32_16x16x32_bf16(ah,blv[n],acc[m][n],0,0,0);
                        acc[m][n]=__builtin_amdgcn_mfma_f32_16x16x32_bf16(al,bhv[n],acc[m][n],0,0,0);
                    }
                } else {
                    #pragma unroll
                    for(int n=0;n<NT;++n)
                        acc[m][n]=__builtin_amdgcn_mfma_f32_16x16x32_bf16(ah,bhv[n],acc[m][n],0,0,0);
                }
            }
        }
    }

    const float rs=(float)(1.0/sqrt(1.0+1e-3));
    #pragma unroll
    for(int n=0;n<NT;++n){
        int col=n0+n*16+l15;
        float bi=bias[col];
        float gsc=0.f, bt=0.f;
        if constexpr(HASBN){ gsc=gamma[col]*rs; bt=beta[col]; }
        #pragma unroll
        for(int m=0;m<MT;++m){
            #pragma unroll
            for(int j=0;j<4;++j){
                size_t g=(size_t)m0 + wr*64 + m*16 + lq*4 + j;
                float vx=acc[m][n][j]+bi;
                if constexpr(HASBN) vx=fmaxf(fmaf(vx,gsc,bt),0.f);
                if constexpr(OUTFMT==0){
                    out_f[g*OC+col]=vx;
                } else if constexpr(OUTFMT==1){
                    ushort h=bf16_hi(vx);
                    ushort lo=bf16_hi(vx-bf16_tof(h));
                    out_pk[g*OC+col]=(uint)h | ((uint)lo<<16);
                } else {
                    out_bf[g*OC+col]=bf16_hi(vx);
                }
            }
        }
    }
}

// ---------------------------------------------------------------------------
// prep: transpose codebook, code norms, zero accumulators + worklist count
// ---------------------------------------------------------------------------
__global__ __launch_bounds__(256)
void prep_k(const float* __restrict__ book, float* __restrict__ ubt,
            float* __restrict__ cbn, float* __restrict__ acc, int* __restrict__ cnt)
{
    for (int i = threadIdx.x; i < K * CB; i += 256) {
        int k = i >> 9, c = i & 511;
        ubt[c * 64 + k] = book[i];
    }
    if (threadIdx.x < 64) {
        const float* r = book + threadIdx.x * 512;
        float s = 0.f;
        for (int c = 0; c < 512; ++c) s = fmaf(r[c], r[c], s);
        cbn[threadIdx.x] = s;
    }
    if (threadIdx.x < 2) acc[threadIdx.x] = 0.f;
    if (threadIdx.x == 0) *cnt = 0;
}

// ---------------------------------------------------------------------------
// NN search (f32): wave per 4 rows, lane = code. best + runner-up;
// gap <= MARGIN -> worklist for f64 re-verification. loss2 accumulated.
// ---------------------------------------------------------------------------
__global__ __launch_bounds__(256)
void nn_k(const float* __restrict__ xenc, const float* __restrict__ ubt,
          const float* __restrict__ cbn, int* __restrict__ qidx,
          float* __restrict__ acc, int* __restrict__ cnt, int* __restrict__ wl)
{
    const int lane = threadIdx.x & 63;
    const int wave = threadIdx.x >> 6;
    const int wid  = blockIdx.x * 4 + wave;
    const int row0 = wid * 4;
    const float* x0 = xenc + (size_t)row0 * 512;

    float dot[4] = {0.f,0.f,0.f,0.f};
    float xn[4]  = {0.f,0.f,0.f,0.f};
    for (int c = 0; c < 512; ++c) {
        float ub = ubt[c * 64 + lane];
        float a0 = x0[c], a1 = x0[512+c], a2 = x0[1024+c], a3 = x0[1536+c];
        dot[0] = fmaf(a0, ub, dot[0]);  xn[0] = fmaf(a0, a0, xn[0]);
        dot[1] = fmaf(a1, ub, dot[1]);  xn[1] = fmaf(a1, a1, xn[1]);
        dot[2] = fmaf(a2, ub, dot[2]);  xn[2] = fmaf(a2, a2, xn[2]);
        dot[3] = fmaf(a3, ub, dot[3]);  xn[3] = fmaf(a3, a3, xn[3]);
    }

    float l2sum = 0.f;
    #pragma unroll
    for (int j = 0; j < 4; ++j) {
        float d1 = cbn[lane] - 2.f * dot[j];
        int   k1 = lane;
        float d2 = 3.4e38f;
        #pragma unroll
        for (int off = 32; off > 0; off >>= 1) {
            float od1 = __shfl_xor(d1, off);
            int   ok1 = __shfl_xor(k1, off);
            float od2 = __shfl_xor(d2, off);
            if (od1 < d1 || (od1 == d1 && ok1 < k1)) {
                d2 = fminf(d1, od2); d1 = od1; k1 = ok1;
            } else {
                d2 = fminf(d2, od1);
            }
        }
        if (lane == 0) {
            qidx[row0 + j] = k1;
            if (d2 - d1 <= MARGIN) { int t = atomicAdd(cnt, 1); wl[t] = row0 + j; }
            l2sum += d1 + xn[j];
        }
    }
    if (lane == 0) atomicAdd(acc + 1, l2sum);
}

// ---------------------------------------------------------------------------
// f64 re-verification of flagged rows (full receptive field from scratch).
// ---------------------------------------------------------------------------
__global__ __launch_bounds__(256)
void recompute_k(const int* __restrict__ wl, const int* __restrict__ cnt,
                 const int* __restrict__ ids, const int* __restrict__ masks,
                 const float* __restrict__ table, const float* __restrict__ book,
                 const float* __restrict__ e_w1, const float* __restrict__ e_b1,
                 const float* __restrict__ e_g1, const float* __restrict__ e_be1,
                 const float* __restrict__ e_w2, const float* __restrict__ e_b2,
                 const float* __restrict__ e_g2, const float* __restrict__ e_be2,
                 const float* __restrict__ e_w3, const float* __restrict__ e_b3,
                 int* __restrict__ qidx)
{
    __shared__ double s_h[16*64];
    __shared__ double s_a1[9*128];
    __shared__ double s_a2[4*256];
    __shared__ double s_x[512];
    __shared__ double s_d[256];

    const int tid = threadIdx.x;
    const double rs = 1.0 / sqrt(1.0 + 1e-3);
    const int n = *cnt;

    for (int wi = blockIdx.x; wi < n; wi += gridDim.x) {
        const int row = wl[wi];
        const int b = row / 49, p = row % 49;
        const int py = p / 7, px = p % 7;

        for (int i = tid; i < 16*64; i += 256) {
            int cell = i >> 6, d = i & 63;
            int l = (py + (cell >> 2)) * 10 + (px + (cell & 3));
            int id = ids[b*100 + l];
            double m = (masks[b*100 + l] >= 1) ? 1.0 : 0.0;
            s_h[i] = (double)table[(size_t)id*64 + d] * m;
        }
        __syncthreads();

        for (int i = tid; i < 9*128; i += 256) {
            int cell = i >> 7, oc = i & 127;
            int ry = cell / 3, rx = cell % 3;
            double s = 0.0;
            #pragma unroll
            for (int kk = 0; kk < 4; ++kk) {
                int icell = (ry + (kk>>1))*4 + (rx + (kk&1));
                const double* hh = s_h + icell*64;
                const float* ww = e_w1 + (kk*64)*128 + oc;
                for (int ic = 0; ic < 64; ++ic)
                    s = fma(hh[ic], (double)ww[ic*128], s);
            }
            s += (double)e_b1[oc];
            s = s * ((double)e_g1[oc] * rs) + (double)e_be1[oc];
            s_a1[i] = s > 0.0 ? s : 0.0;
        }
        __syncthreads();

        for (int i = tid; i < 4*256; i += 256) {
            int cell = i >> 8, oc = i & 255;
            int qy = cell >> 1, qx = cell & 1;
            double s = 0.0;
            #pragma unroll
            for (int kk = 0; kk < 4; ++kk) {
                int icell = (qy + (kk>>1))*3 + (qx + (kk&1));
                const double* aa = s_a1 + icell*128;
                const float* ww = e_w2 + (kk*128)*256 + oc;
                for (int ic = 0; ic < 128; ++ic)
                    s = fma(aa[ic], (double)ww[ic*256], s);
            }
            s += (double)e_b2[oc];
            s = s * ((double)e_g2[oc] * rs) + (double)e_be2[oc];
            s_a2[i] = s > 0.0 ? s : 0.0;
        }
        __syncthreads();

        for (int i = tid; i < 512; i += 256) {
            double s = 0.0;
            #pragma unroll
            for (int kk = 0; kk < 4; ++kk) {
                const double* aa = s_a2 + kk*256;
                const float* ww = e_w3 + (kk*256)*512 + i;
                for (int ic = 0; ic < 256; ++ic)
                    s = fma(aa[ic], (double)ww[ic*512], s);
            }
            s_x[i] = s + (double)e_b3[i];
        }
        __syncthreads();

        {
            int k = tid & 63, seg = tid >> 6;
            const float* cr = book + k*512 + seg*128;
            const double* xr = s_x + seg*128;
            double s = 0.0;
            for (int c = 0; c < 128; ++c) {
                double dd = xr[c] - (double)cr[c];
                s = fma(dd, dd, s);
            }
            s_d[seg*64 + k] = s;
        }
        __syncthreads();

        if (tid < 64) {
            double dv = s_d[tid] + s_d[64+tid] + s_d[128+tid] + s_d[192+tid];
            int kk2 = tid;
            #pragma unroll
            for (int off = 32; off > 0; off >>= 1) {
                double od = __shfl_xor(dv, off);
                int    ok = __shfl_xor(kk2, off);
                if (od < dv || (od == dv && ok < kk2)) { dv = od; kk2 = ok; }
            }
            if (tid == 0) qidx[row] = kk2;
        }
        __syncthreads();
    }
}

// ---------------------------------------------------------------------------
// finalize: loss1 = sum (hist - vq_x)^2, vq_mean
// ---------------------------------------------------------------------------
__global__ __launch_bounds__(256)
void finalize_k(const float* __restrict__ vqx, const int* __restrict__ ids,
                const int* __restrict__ masks, const float* __restrict__ table,
                float* __restrict__ out_mean, float* __restrict__ acc)
{
    const int b = blockIdx.x;
    const int tid = threadIdx.x;
    const float* vb = vqx + (size_t)b * 6400;

    float part = 0.f;
    for (int i = tid; i < 6400; i += 256) {
        int l = i >> 6, d = i & 63;
        int id = ids[b * L + l];
        float m = (masks[b * L + l] >= 1) ? 1.f : 0.f;
        float h = table[(size_t)id * 64 + d] * m;
        float diff = h - vb[i];
        part = fmaf(diff, diff, part);
    }
    __shared__ float s_red[4];
    #pragma unroll
    for (int off = 32; off > 0; off >>= 1) part += __shfl_down(part, off);
    if ((tid & 63) == 0) s_red[tid >> 6] = part;
    __syncthreads();
    if (tid == 0) atomicAdd(acc + 0, s_red[0] + s_red[1] + s_red[2] + s_red[3]);

    if (tid < 64) {
        float msum = 0.f;
        for (int l = 0; l < L; ++l) msum += (masks[b * L + l] >= 1) ? 1.f : 0.f;
        float s = 0.f;
        for (int l = 0; l < L; ++l) s += vb[l * 64 + tid];
        out_mean[b * 64 + tid] = s / msum;
    }
}

__global__ void loss_k(const float* __restrict__ acc, float* __restrict__ out_loss)
{
    float l1 = acc[0] / 13107200.f;
    float l2 = acc[1] / 51380224.f;
    out_loss[0] = l1 + l2 + 0.25f * l2;
}

// ---------------------------------------------------------------------------
extern "C" void kernel_launch(void* const* d_in, const int* in_sizes, int n_in,
                              void* d_out, int out_size, void* d_ws, size_t ws_size,
                              hipStream_t stream)
{
    const int*   ids   = (const int*)d_in[0];
    const int*   masks = (const int*)d_in[1];
    const float* table = (const float*)d_in[2];
    const float* book  = (const float*)d_in[3];
    const float* e_w1  = (const float*)d_in[4];
    const float* e_b1  = (const float*)d_in[5];
    const float* e_g1  = (const float*)d_in[6];
    const float* e_be1 = (const float*)d_in[7];
    const float* e_w2  = (const float*)d_in[8];
    const float* e_b2  = (const float*)d_in[9];
    const float* e_g2  = (const float*)d_in[10];
    const float* e_be2 = (const float*)d_in[11];
    const float* e_w3  = (const float*)d_in[12];
    const float* e_b3  = (const float*)d_in[13];
    const float* d_w1  = (const float*)d_in[14];
    const float* d_b1  = (const float*)d_in[15];
    const float* d_g1  = (const float*)d_in[16];
    const float* d_be1 = (const float*)d_in[17];
    const float* d_w2  = (const float*)d_in[18];
    const float* d_b2  = (const float*)d_in[19];
    const float* d_g2  = (const float*)d_in[20];
    const float* d_be2 = (const float*)d_in[21];
    const float* d_w3  = (const float*)d_in[22];
    const float* d_b3  = (const float*)d_in[23];

    float*  ws  = (float*)d_ws;
    uint*   A1P = (uint*)(ws + R0_OFF);   // [B*81*128] u32 hi|lo
    uint*   A2P = (uint*)(ws + R1_OFF);   // [B*64*256] u32 hi|lo
    float*  XE  = ws + R0_OFF;            // [B*49*512] f32
    ushort* G1  = (ushort*)(ws + R1_OFF); // [B*64*256] bf16
    ushort* G2  = (ushort*)(ws + R0_OFF); // [B*81*128] bf16
    int*    IDX = (int*)(ws + IDX_OFF);
    float*  UBT = ws + UBT_OFF;
    float*  CBN = ws + CBN_OFF;
    int*    CNT = (int*)(ws + CNT_OFF);
    float*  ACC = ws + ACC_OFF;
    int*    WL  = (int*)(ws + WL_OFF);
    ushort* WB  = (ushort*)(ws + WB_OFF);

    float* out_mean = (float*)d_out;
    float* out_vqx  = (float*)d_out + (size_t)B * 64;
    float* out_loss = (float*)d_out + (size_t)B * 64 + (size_t)B * L * 64;

    prep_k<<<1, 256, 0, stream>>>(book, UBT, CBN, ACC, CNT);
    wprep_k<<<512, 256, 0, stream>>>(e_w1, e_w2, e_w3, d_w1, d_w2, d_w3, book, WB);

    // encoder (split-bf16): M = B*NPOS, NM = 16*NPOS
    bconv_k<10,10, 64,128,0,1,true ,true ,1,128,1><<<1296,256,0,stream>>>(
        nullptr, nullptr, ids, masks, table, nullptr, nullptr,
        WB+EW1H, WB+EW1L, e_b1, e_g1, e_be1, nullptr, A1P, nullptr);
    bconv_k< 9, 9,128,256,0,3,true ,true ,2,128,1><<<2048,256,0,stream>>>(
        A1P, nullptr, nullptr, nullptr, nullptr, nullptr, nullptr,
        WB+EW2H, WB+EW2L, e_b2, e_g2, e_be2, nullptr, A2P, nullptr);
    bconv_k< 8, 8,256,512,0,3,false,true ,4,128,0><<<3136,256,0,stream>>>(
        A2P, nullptr, nullptr, nullptr, nullptr, nullptr, nullptr,
        WB+EW3H, WB+EW3L, e_b3, nullptr, nullptr, XE, nullptr, nullptr);

    // codebook NN (f32 + margin flag) then f64 re-verify of flagged rows
    nn_k<<<6272, 256, 0, stream>>>(XE, UBT, CBN, IDX, ACC, CNT, WL);
    recompute_k<<<512, 256, 0, stream>>>(WL, CNT, ids, masks, table, book,
                                         e_w1, e_b1, e_g1, e_be1,
                                         e_w2, e_b2, e_g2, e_be2,
                                         e_w3, e_b3, IDX);

    // decoder (plain bf16; conv_transpose == conv pad=1, unflipped kernel)
    bconv_k< 7, 7,512,256,1,2,true ,false,2,128,2><<<2048,256,0,stream>>>(
        nullptr, nullptr, nullptr, nullptr, nullptr, IDX, WB+BKB,
        WB+DW1H, nullptr, d_b1, d_g1, d_be1, nullptr, nullptr, G1);
    bconv_k< 8, 8,256,128,1,4,true ,false,1,128,2><<<1296,256,0,stream>>>(
        nullptr, G1, nullptr, nullptr, nullptr, nullptr, nullptr,
        WB+DW2H, nullptr, d_b2, d_g2, d_be2, nullptr, nullptr, G2);
    bconv_k< 9, 9,128, 64,1,4,false,false,1, 64,0><<<1600,256,0,stream>>>(
        nullptr, G2, nullptr, nullptr, nullptr, nullptr, nullptr,
        WB+DW3H, nullptr, d_b3, nullptr, nullptr, out_vqx, nullptr, nullptr);

    // vq_mean + loss1, then scalar loss
    finalize_k<<<B, 256, 0, stream>>>(out_vqx, ids, masks, table, out_mean, ACC);
    loss_k<<<1, 1, 0, stream>>>(ACC, out_loss);
}

// Round 9
// 2037.746 us; speedup vs baseline: 1.1993x; 1.1993x over previous
//
#include <hip/hip_runtime.h>
#include <hip/hip_bf16.h>
#include <cstdint>
#include <cstddef>

// ---------------------------------------------------------------------------
// VQ-VAE forward (B=2048, L=100, D=64, K=64, CB=512) — per-sample MFMA v4.
// Round-7 dataflow + this round: LDS double-buffer (ONE barrier per chunk),
// T14 load-after-barrier prefetch, s_setprio around MFMA clusters, wider
// N-tiles (conv3 OCS=2 NT=4, deconv1 OCS=1 NT=4), hoisted arow tables.
// Encoder: split-bf16 (3 MFMAs) ~f32; decoder: plain bf16.
// Argmin exactness: margin 0.1 -> f64 full recompute of flagged rows.
// ---------------------------------------------------------------------------

typedef __attribute__((ext_vector_type(8))) short short8v;   // 8 bf16
typedef __attribute__((ext_vector_type(4))) float f32x4;

constexpr int B  = 2048;
constexpr int L  = 100;
constexpr int K  = 64;
constexpr int CB = 512;
#define MARGIN 0.1f

// ---- workspace layout (float-sized units) ----
constexpr size_t R0_OFF  = 0;          // A1P u32 -> XE f32 -> G2 bf16
constexpr size_t R1_OFF  = 51380224;   // A2P u32 -> G1 bf16
constexpr size_t IDX_OFF = 84934656;   // 2048*49 ints
constexpr size_t UBT_OFF = 85035008;   // 512*64 f32 transposed codebook
constexpr size_t CBN_OFF = 85067776;   // 64 norms
constexpr size_t CNT_OFF = 85067840;
constexpr size_t ACC_OFF = 85067856;
constexpr size_t WL_OFF  = 85067872;   // 100352 ints
constexpr size_t WB_OFF  = 85168224;   // bf16 weights (ushort units below)

// bf16 weight sub-offsets (ushort units), layout [4][OC][IC]
constexpr size_t EW1H=0,       EW1L=32768;
constexpr size_t EW2H=65536,   EW2L=196608;
constexpr size_t EW3H=327680,  EW3L=851968;
constexpr size_t DW1H=1376256, DW2H=1900544, DW3H=2031616;
constexpr size_t BKB =2064384;  // book bf16 [64][512]

__device__ inline ushort bf16_hi(float f){ __hip_bfloat16 h=__float2bfloat16(f); return *(ushort*)&h; }
__device__ inline float  bf16_tof(ushort u){ __hip_bfloat16 h; *(ushort*)&h=u; return __bfloat162float(h); }

// ---------------------------------------------------------------------------
// weight prep: w[2,2,IC,OC] f32 -> Wt[kk][oc][ic] bf16 hi (+lo for encoder);
// book -> bf16.
// ---------------------------------------------------------------------------
__device__ void wtrans(const float* __restrict__ w, int IC, int OC,
                       ushort* __restrict__ hi, ushort* __restrict__ lo,
                       int gid, int gsz)
{
    int tot = 4*IC*OC;
    for (int i = gid; i < tot; i += gsz) {
        int kk = i/(IC*OC), r = i - kk*(IC*OC), ic = r/OC, oc = r - ic*OC;
        float v = w[i];
        ushort h = bf16_hi(v);
        size_t dst = ((size_t)kk*OC + oc)*IC + ic;
        hi[dst] = h;
        if (lo) lo[dst] = bf16_hi(v - bf16_tof(h));
    }
}

__global__ __launch_bounds__(256)
void wprep_k(const float* e1, const float* e2, const float* e3,
             const float* d1, const float* d2, const float* d3,
             const float* book, ushort* wb)
{
    int gid = blockIdx.x*256 + threadIdx.x, gsz = gridDim.x*256;
    wtrans(e1,  64, 128, wb+EW1H, wb+EW1L, gid, gsz);
    wtrans(e2, 128, 256, wb+EW2H, wb+EW2L, gid, gsz);
    wtrans(e3, 256, 512, wb+EW3H, wb+EW3L, gid, gsz);
    wtrans(d1, 512, 256, wb+DW1H, nullptr, gid, gsz);
    wtrans(d2, 256, 128, wb+DW2H, nullptr, gid, gsz);
    wtrans(d3, 128,  64, wb+DW3H, nullptr, gid, gsz);
    for (int i = gid; i < 64*512; i += gsz) wb[BKB+i] = bf16_hi(book[i]);
}

// ---------------------------------------------------------------------------
// Per-sample MFMA conv. Block = (sample b, oc-slice sl), XCD-remapped.
// 4 waves split the slice's OC. LDS: double-buffered ICC-chunk of all rows
// (+zero row), XOR-swizzled. Loop: [load(c+1) after barrier | setprio(1)
// MFMA(buf c) setprio(0) | write(buf c+1) barrier].
// MODE 1: table gather+mask; 2: book bf16 via qidx; 3: packed u32 hi|lo;
// 4: bf16.  OUTFMT 0: f32; 1: packed u32; 2: bf16.
// FUSE: deconv3 epilogue computes vq_mean and accumulates loss1.
// ---------------------------------------------------------------------------
template<int IH,int IW,int IC,int OC,int PAD,int MODE,bool HASBN,bool SPLIT,
         int OCS,int ICC,int MT,int OUTFMT,bool FUSE>
__global__ __launch_bounds__(256)
void sconv_k(const uint* __restrict__ in_pk, const ushort* __restrict__ in_bf,
             const int* __restrict__ ids, const int* __restrict__ masks,
             const float* __restrict__ table,
             const int* __restrict__ qidx, const ushort* __restrict__ bookbf,
             const ushort* __restrict__ wt_hi, const ushort* __restrict__ wt_lo,
             const float* __restrict__ bias, const float* __restrict__ gamma,
             const float* __restrict__ beta,
             float* __restrict__ out_f, uint* __restrict__ out_pk,
             ushort* __restrict__ out_bf, float* __restrict__ out_mean,
             float* __restrict__ acc_g)
{
    constexpr int OH=IH+2*PAD-1, OW=IW+2*PAD-1, NPOS=OH*OW, IHW=IH*IW;
    constexpr int OCB=OC/OCS, NPW=OCB/4, NT=NPW/16;
    constexpr int NCH=IC/ICC, KS=ICC/32;
    constexpr int PL=SPLIT?2:1;
    constexpr int NB=(NCH>1)?2:1;
    constexpr int AROWS=IHW+1, RB=ICC*2;
    constexpr int C8=ICC/8;
    constexpr int NITEMS=IHW*C8;
    constexpr int SI=(NITEMS+255)/256;
    constexpr bool EXACT=(SI*256==NITEMS);
    constexpr int BUFB=PL*AROWS*RB;          // bytes per buffer

    __shared__ ushort s_a[NB*PL*AROWS*ICC];
    char* sb=(char*)s_a;

    // XCD-aware remap: all OCS slices of a sample live on one XCD.
    const int v=blockIdx.x, r8=v&7, iv=v>>3;
    const int b = r8*(B/8) + iv/OCS;
    const int sl = iv - (iv/OCS)*OCS;

    const int tid=threadIdx.x, lane=tid&63, wv=tid>>6;
    const int l15=lane&15, lq=lane>>4;
    const int n0=sl*OCB + wv*NPW;

    // per-tap LDS row tables (chunk-invariant)
    int arow[4][MT];
    #pragma unroll
    for(int kk=0;kk<4;++kk){
        const int ky=kk>>1, kx=kk&1;
        #pragma unroll
        for(int m=0;m<MT;++m){
            int p=m*16+l15;
            int py=p/OW, px=p-py*OW;
            int ty=py+ky-PAD, tx=px+kx-PAD;
            bool ok=(p<NPOS)&&((unsigned)ty<(unsigned)IH)&&((unsigned)tx<(unsigned)IW);
            arow[kk][m]= ok ? ty*IW+tx : IHW;
        }
    }

    f32x4 acc[MT][NT];
    #pragma unroll
    for(int m=0;m<MT;++m)
        #pragma unroll
        for(int n=0;n<NT;++n) acc[m][n]=(f32x4)0.0f;

    uint4 r0[SI];
    uint4 r1[(MODE==1||MODE==3)?SI:1];
    float msk[(MODE==1)?SI:1];

    auto stage_load=[&](int c){
        const int ic0=c*ICC;
        #pragma unroll
        for(int t=0;t<SI;++t){
            int idx=tid+t*256;
            if(EXACT || idx<NITEMS){
                int row=idx/C8, g=idx-row*C8;
                if constexpr(MODE==1){
                    int id=ids[b*L+row];
                    msk[t]=(masks[b*L+row]>=1)?1.f:0.f;
                    const float* src=table+(size_t)id*64+g*8;      // ICC==IC==64
                    r0[t]=*(const uint4*)src;
                    r1[t]=*(const uint4*)(src+4);
                } else if constexpr(MODE==2){
                    int kq=qidx[b*49+row];
                    r0[t]=*(const uint4*)(bookbf+(size_t)kq*512+ic0+g*8);
                } else if constexpr(MODE==3){
                    const uint* src=in_pk+((size_t)b*IHW+row)*IC+ic0+g*8;
                    r0[t]=*(const uint4*)src;
                    r1[t]=*(const uint4*)(src+4);
                } else {
                    r0[t]=*(const uint4*)(in_bf+((size_t)b*IHW+row)*IC+ic0+g*8);
                }
            }
        }
    };

    auto stage_write=[&](int bufb){
        #pragma unroll
        for(int t=0;t<SI;++t){
            int idx=tid+t*256;
            if(EXACT || idx<NITEMS){
                int row=idx/C8, g=idx-row*C8;
                int boff=bufb + row*RB + ((g^(row&7))<<4);
                if constexpr(MODE==1){
                    const float* f0=(const float*)&r0[t];
                    const float* f1=(const float*)&r1[t];
                    float vv[8]={f0[0]*msk[t],f0[1]*msk[t],f0[2]*msk[t],f0[3]*msk[t],
                                 f1[0]*msk[t],f1[1]*msk[t],f1[2]*msk[t],f1[3]*msk[t]};
                    ushort hh[8], ll[8];
                    #pragma unroll
                    for(int j=0;j<8;++j){ hh[j]=bf16_hi(vv[j]); ll[j]=bf16_hi(vv[j]-bf16_tof(hh[j])); }
                    *(uint4*)(sb+boff)=*(uint4*)hh;
                    *(uint4*)(sb+AROWS*RB+boff)=*(uint4*)ll;
                } else if constexpr(MODE==3){
                    const uint* u0=(const uint*)&r0[t];
                    const uint* u1=(const uint*)&r1[t];
                    ushort hh[8], ll[8];
                    #pragma unroll
                    for(int j=0;j<4;++j){ hh[j]=(ushort)(u0[j]&0xffffu); ll[j]=(ushort)(u0[j]>>16); }
                    #pragma unroll
                    for(int j=0;j<4;++j){ hh[4+j]=(ushort)(u1[j]&0xffffu); ll[4+j]=(ushort)(u1[j]>>16); }
                    *(uint4*)(sb+boff)=*(uint4*)hh;
                    *(uint4*)(sb+AROWS*RB+boff)=*(uint4*)ll;
                } else {
                    *(uint4*)(sb+boff)=r0[t];
                }
            }
        }
    };

    // prologue: stage chunk 0, zero rows of all buffers/planes, one barrier
    stage_load(0);
    stage_write(0);
    for(int z=tid; z<NB*PL*C8; z+=256){
        int nb=z/(PL*C8), rz=z-nb*(PL*C8), pl=rz/C8, g=rz-pl*C8;
        *(uint4*)(sb + nb*BUFB + pl*(AROWS*RB) + IHW*RB + (g<<4)) = make_uint4(0,0,0,0);
    }
    __syncthreads();

    for(int c=0;c<NCH;++c){
        if(c+1<NCH) stage_load(c+1);          // T14: issue after barrier, fly under MFMAs
        const int bufb=(c&1)*BUFB;
        const int ic0=c*ICC;
        __builtin_amdgcn_s_setprio(1);
        #pragma unroll
        for(int kk=0;kk<4;++kk){
            #pragma unroll
            for(int ks=0;ks<KS;++ks){
                short8v bhv[NT]; short8v blv[SPLIT?NT:1];
                #pragma unroll
                for(int n=0;n<NT;++n){
                    int col=n0+n*16+l15;
                    size_t widx=((size_t)kk*OC+col)*IC+ic0+ks*32+lq*8;
                    bhv[n]=*(const short8v*)(wt_hi+widx);
                    if constexpr(SPLIT) blv[n]=*(const short8v*)(wt_lo+widx);
                }
                #pragma unroll
                for(int m=0;m<MT;++m){
                    int off=bufb + arow[kk][m]*RB + ((((ks<<2)|lq)^(arow[kk][m]&7))<<4);
                    short8v ah=*(const short8v*)(sb+off);
                    if constexpr(SPLIT){
                        short8v al=*(const short8v*)(sb+AROWS*RB+off);
                        #pragma unroll
                        for(int n=0;n<NT;++n){
                            acc[m][n]=__builtin_amdgcn_mfma_f32_16x16x32_bf16(ah,bhv[n],acc[m][n],0,0,0);
                            acc[m][n]=__builtin_amdgcn_mfma_f32_16x16x32_bf16(ah,blv[n],acc[m][n],0,0,0);
                            acc[m][n]=__builtin_amdgcn_mfma_f32_16x16x32_bf16(al,bhv[n],acc[m][n],0,0,0);
                        }
                    } else {
                        #pragma unroll
                        for(int n=0;n<NT;++n)
                            acc[m][n]=__builtin_amdgcn_mfma_f32_16x16x32_bf16(ah,bhv[n],acc[m][n],0,0,0);
                    }
                }
            }
        }
        __builtin_amdgcn_s_setprio(0);
        if(c+1<NCH){
            stage_write(((c+1)&1)*BUFB);      // other buffer: no read hazard
            __syncthreads();                  // ONE barrier per chunk
        }
    }

    const float rs=(float)(1.0/sqrt(1.0+1e-3));
    float lsum=0.f, colsum=0.f;
    #pragma unroll
    for(int n=0;n<NT;++n){
        int col=n0+n*16+l15;
        float bi=bias[col];
        float gsc=0.f, bt=0.f;
        if constexpr(HASBN){ gsc=gamma[col]*rs; bt=beta[col]; }
        #pragma unroll
        for(int m=0;m<MT;++m){
            #pragma unroll
            for(int j=0;j<4;++j){
                int p=m*16+lq*4+j;
                if(p<NPOS){
                    float vx=acc[m][n][j]+bi;
                    if constexpr(HASBN) vx=fmaxf(fmaf(vx,gsc,bt),0.f);
                    size_t g=(size_t)b*NPOS+p;
                    if constexpr(OUTFMT==0){
                        out_f[g*OC+col]=vx;
                    } else if constexpr(OUTFMT==1){
                        ushort h=bf16_hi(vx);
                        ushort lo=bf16_hi(vx-bf16_tof(h));
                        out_pk[g*OC+col]=(uint)h | ((uint)lo<<16);
                    } else {
                        out_bf[g*OC+col]=bf16_hi(vx);
                    }
                    if constexpr(FUSE){
                        int id=ids[b*L+p];
                        float mm=(masks[b*L+p]>=1)?1.f:0.f;
                        float h=table[(size_t)id*64+col]*mm;
                        float df=h-vx;
                        lsum=fmaf(df,df,lsum);
                        colsum+=vx;
                    }
                }
            }
        }
    }

    if constexpr(FUSE){
        float mc=0.f;
        for(int l=lane;l<L;l+=64) mc += (masks[b*L+l]>=1)?1.f:0.f;
        #pragma unroll
        for(int off=32;off;off>>=1) mc+=__shfl_xor(mc,off);
        colsum += __shfl_xor(colsum,16);
        colsum += __shfl_xor(colsum,32);
        if(lq==0) out_mean[b*64 + n0 + l15] = colsum/mc;
        #pragma unroll
        for(int off=32;off;off>>=1) lsum+=__shfl_xor(lsum,off);
        __syncthreads();
        float* red=(float*)sb;
        if(lane==0) red[wv]=lsum;
        __syncthreads();
        if(tid==0) atomicAdd(acc_g+0, red[0]+red[1]+red[2]+red[3]);
    }
}

// ---------------------------------------------------------------------------
// prep: transpose codebook, code norms, zero accumulators + worklist count
// ---------------------------------------------------------------------------
__global__ __launch_bounds__(256)
void prep_k(const float* __restrict__ book, float* __restrict__ ubt,
            float* __restrict__ cbn, float* __restrict__ acc, int* __restrict__ cnt)
{
    for (int i = threadIdx.x; i < K * CB; i += 256) {
        int k = i >> 9, c = i & 511;
        ubt[c * 64 + k] = book[i];
    }
    if (threadIdx.x < 64) {
        const float* r = book + threadIdx.x * 512;
        float s = 0.f;
        for (int c = 0; c < 512; ++c) s = fmaf(r[c], r[c], s);
        cbn[threadIdx.x] = s;
    }
    if (threadIdx.x < 2) acc[threadIdx.x] = 0.f;
    if (threadIdx.x == 0) *cnt = 0;
}

// ---------------------------------------------------------------------------
// NN search (f32): wave per 4 rows, lane = code. best + runner-up;
// gap <= MARGIN -> worklist for f64 re-verification. loss2 accumulated.
// ---------------------------------------------------------------------------
__global__ __launch_bounds__(256)
void nn_k(const float* __restrict__ xenc, const float* __restrict__ ubt,
          const float* __restrict__ cbn, int* __restrict__ qidx,
          float* __restrict__ acc, int* __restrict__ cnt, int* __restrict__ wl)
{
    const int lane = threadIdx.x & 63;
    const int wave = threadIdx.x >> 6;
    const int wid  = blockIdx.x * 4 + wave;
    const int row0 = wid * 4;
    const float* x0 = xenc + (size_t)row0 * 512;

    float dot[4] = {0.f,0.f,0.f,0.f};
    float xn[4]  = {0.f,0.f,0.f,0.f};
    for (int c = 0; c < 512; ++c) {
        float ub = ubt[c * 64 + lane];
        float a0 = x0[c], a1 = x0[512+c], a2 = x0[1024+c], a3 = x0[1536+c];
        dot[0] = fmaf(a0, ub, dot[0]);  xn[0] = fmaf(a0, a0, xn[0]);
        dot[1] = fmaf(a1, ub, dot[1]);  xn[1] = fmaf(a1, a1, xn[1]);
        dot[2] = fmaf(a2, ub, dot[2]);  xn[2] = fmaf(a2, a2, xn[2]);
        dot[3] = fmaf(a3, ub, dot[3]);  xn[3] = fmaf(a3, a3, xn[3]);
    }

    float l2sum = 0.f;
    #pragma unroll
    for (int j = 0; j < 4; ++j) {
        float d1 = cbn[lane] - 2.f * dot[j];
        int   k1 = lane;
        float d2 = 3.4e38f;
        #pragma unroll
        for (int off = 32; off > 0; off >>= 1) {
            float od1 = __shfl_xor(d1, off);
            int   ok1 = __shfl_xor(k1, off);
            float od2 = __shfl_xor(d2, off);
            if (od1 < d1 || (od1 == d1 && ok1 < k1)) {
                d2 = fminf(d1, od2); d1 = od1; k1 = ok1;
            } else {
                d2 = fminf(d2, od1);
            }
        }
        if (lane == 0) {
            qidx[row0 + j] = k1;
            if (d2 - d1 <= MARGIN) { int t = atomicAdd(cnt, 1); wl[t] = row0 + j; }
            l2sum += d1 + xn[j];
        }
    }
    if (lane == 0) atomicAdd(acc + 1, l2sum);
}

// ---------------------------------------------------------------------------
// f64 re-verification of flagged rows (full receptive field from scratch).
// ---------------------------------------------------------------------------
__global__ __launch_bounds__(256)
void recompute_k(const int* __restrict__ wl, const int* __restrict__ cnt,
                 const int* __restrict__ ids, const int* __restrict__ masks,
                 const float* __restrict__ table, const float* __restrict__ book,
                 const float* __restrict__ e_w1, const float* __restrict__ e_b1,
                 const float* __restrict__ e_g1, const float* __restrict__ e_be1,
                 const float* __restrict__ e_w2, const float* __restrict__ e_b2,
                 const float* __restrict__ e_g2, const float* __restrict__ e_be2,
                 const float* __restrict__ e_w3, const float* __restrict__ e_b3,
                 int* __restrict__ qidx)
{
    __shared__ double s_h[16*64];
    __shared__ double s_a1[9*128];
    __shared__ double s_a2[4*256];
    __shared__ double s_x[512];
    __shared__ double s_d[256];

    const int tid = threadIdx.x;
    const double rs = 1.0 / sqrt(1.0 + 1e-3);
    const int n = *cnt;

    for (int wi = blockIdx.x; wi < n; wi += gridDim.x) {
        const int row = wl[wi];
        const int b = row / 49, p = row % 49;
        const int py = p / 7, px = p % 7;

        for (int i = tid; i < 16*64; i += 256) {
            int cell = i >> 6, d = i & 63;
            int l = (py + (cell >> 2)) * 10 + (px + (cell & 3));
            int id = ids[b*100 + l];
            double m = (masks[b*100 + l] >= 1) ? 1.0 : 0.0;
            s_h[i] = (double)table[(size_t)id*64 + d] * m;
        }
        __syncthreads();

        for (int i = tid; i < 9*128; i += 256) {
            int cell = i >> 7, oc = i & 127;
            int ry = cell / 3, rx = cell % 3;
            double s = 0.0;
            #pragma unroll
            for (int kk = 0; kk < 4; ++kk) {
                int icell = (ry + (kk>>1))*4 + (rx + (kk&1));
                const double* hh = s_h + icell*64;
                const float* ww = e_w1 + (kk*64)*128 + oc;
                for (int ic = 0; ic < 64; ++ic)
                    s = fma(hh[ic], (double)ww[ic*128], s);
            }
            s += (double)e_b1[oc];
            s = s * ((double)e_g1[oc] * rs) + (double)e_be1[oc];
            s_a1[i] = s > 0.0 ? s : 0.0;
        }
        __syncthreads();

        for (int i = tid; i < 4*256; i += 256) {
            int cell = i >> 8, oc = i & 255;
            int qy = cell >> 1, qx = cell & 1;
            double s = 0.0;
            #pragma unroll
            for (int kk = 0; kk < 4; ++kk) {
                int icell = (qy + (kk>>1))*3 + (qx + (kk&1));
                const double* aa = s_a1 + icell*128;
                const float* ww = e_w2 + (kk*128)*256 + oc;
                for (int ic = 0; ic < 128; ++ic)
                    s = fma(aa[ic], (double)ww[ic*256], s);
            }
            s += (double)e_b2[oc];
            s = s * ((double)e_g2[oc] * rs) + (double)e_be2[oc];
            s_a2[i] = s > 0.0 ? s : 0.0;
        }
        __syncthreads();

        for (int i = tid; i < 512; i += 256) {
            double s = 0.0;
            #pragma unroll
            for (int kk = 0; kk < 4; ++kk) {
                const double* aa = s_a2 + kk*256;
                const float* ww = e_w3 + (kk*256)*512 + i;
                for (int ic = 0; ic < 256; ++ic)
                    s = fma(aa[ic], (double)ww[ic*512], s);
            }
            s_x[i] = s + (double)e_b3[i];
        }
        __syncthreads();

        {
            int k = tid & 63, seg = tid >> 6;
            const float* cr = book + k*512 + seg*128;
            const double* xr = s_x + seg*128;
            double s = 0.0;
            for (int c = 0; c < 128; ++c) {
                double dd = xr[c] - (double)cr[c];
                s = fma(dd, dd, s);
            }
            s_d[seg*64 + k] = s;
        }
        __syncthreads();

        if (tid < 64) {
            double dv = s_d[tid] + s_d[64+tid] + s_d[128+tid] + s_d[192+tid];
            int kk2 = tid;
            #pragma unroll
            for (int off = 32; off > 0; off >>= 1) {
                double od = __shfl_xor(dv, off);
                int    ok = __shfl_xor(kk2, off);
                if (od < dv || (od == dv && ok < kk2)) { dv = od; kk2 = ok; }
            }
            if (tid == 0) qidx[row] = kk2;
        }
        __syncthreads();
    }
}

__global__ void loss_k(const float* __restrict__ acc, float* __restrict__ out_loss)
{
    float l1 = acc[0] / 13107200.f;
    float l2 = acc[1] / 51380224.f;
    out_loss[0] = l1 + l2 + 0.25f * l2;
}

// ---------------------------------------------------------------------------
extern "C" void kernel_launch(void* const* d_in, const int* in_sizes, int n_in,
                              void* d_out, int out_size, void* d_ws, size_t ws_size,
                              hipStream_t stream)
{
    const int*   ids   = (const int*)d_in[0];
    const int*   masks = (const int*)d_in[1];
    const float* table = (const float*)d_in[2];
    const float* book  = (const float*)d_in[3];
    const float* e_w1  = (const float*)d_in[4];
    const float* e_b1  = (const float*)d_in[5];
    const float* e_g1  = (const float*)d_in[6];
    const float* e_be1 = (const float*)d_in[7];
    const float* e_w2  = (const float*)d_in[8];
    const float* e_b2  = (const float*)d_in[9];
    const float* e_g2  = (const float*)d_in[10];
    const float* e_be2 = (const float*)d_in[11];
    const float* e_w3  = (const float*)d_in[12];
    const float* e_b3  = (const float*)d_in[13];
    const float* d_w1  = (const float*)d_in[14];
    const float* d_b1  = (const float*)d_in[15];
    const float* d_g1  = (const float*)d_in[16];
    const float* d_be1 = (const float*)d_in[17];
    const float* d_w2  = (const float*)d_in[18];
    const float* d_b2  = (const float*)d_in[19];
    const float* d_g2  = (const float*)d_in[20];
    const float* d_be2 = (const float*)d_in[21];
    const float* d_w3  = (const float*)d_in[22];
    const float* d_b3  = (const float*)d_in[23];

    float*  ws  = (float*)d_ws;
    uint*   A1P = (uint*)(ws + R0_OFF);   // [B*81*128] u32 hi|lo
    uint*   A2P = (uint*)(ws + R1_OFF);   // [B*64*256] u32 hi|lo
    float*  XE  = ws + R0_OFF;            // [B*49*512] f32
    ushort* G1  = (ushort*)(ws + R1_OFF); // [B*64*256] bf16
    ushort* G2  = (ushort*)(ws + R0_OFF); // [B*81*128] bf16
    int*    IDX = (int*)(ws + IDX_OFF);
    float*  UBT = ws + UBT_OFF;
    float*  CBN = ws + CBN_OFF;
    int*    CNT = (int*)(ws + CNT_OFF);
    float*  ACC = ws + ACC_OFF;
    int*    WL  = (int*)(ws + WL_OFF);
    ushort* WB  = (ushort*)(ws + WB_OFF);

    float* out_mean = (float*)d_out;
    float* out_vqx  = (float*)d_out + (size_t)B * 64;
    float* out_loss = (float*)d_out + (size_t)B * 64 + (size_t)B * L * 64;

    prep_k<<<1, 256, 0, stream>>>(book, UBT, CBN, ACC, CNT);
    wprep_k<<<512, 256, 0, stream>>>(e_w1, e_w2, e_w3, d_w1, d_w2, d_w3, book, WB);

    // encoder (split-bf16)
    sconv_k<10,10, 64,128,0,1,true ,true ,1, 64,6,1,false><<<B,   256,0,stream>>>(
        nullptr, nullptr, ids, masks, table, nullptr, nullptr,
        WB+EW1H, WB+EW1L, e_b1, e_g1, e_be1, nullptr, A1P, nullptr, nullptr, nullptr);
    sconv_k< 9, 9,128,256,0,3,true ,true ,2, 64,4,1,false><<<B*2, 256,0,stream>>>(
        A1P, nullptr, nullptr, nullptr, nullptr, nullptr, nullptr,
        WB+EW2H, WB+EW2L, e_b2, e_g2, e_be2, nullptr, A2P, nullptr, nullptr, nullptr);
    sconv_k< 8, 8,256,512,0,3,false,true ,2, 64,4,0,false><<<B*2, 256,0,stream>>>(
        A2P, nullptr, nullptr, nullptr, nullptr, nullptr, nullptr,
        WB+EW3H, WB+EW3L, e_b3, nullptr, nullptr, XE, nullptr, nullptr, nullptr, nullptr);

    // codebook NN (f32 + margin flag) then f64 re-verify of flagged rows
    nn_k<<<6272, 256, 0, stream>>>(XE, UBT, CBN, IDX, ACC, CNT, WL);
    recompute_k<<<512, 256, 0, stream>>>(WL, CNT, ids, masks, table, book,
                                         e_w1, e_b1, e_g1, e_be1,
                                         e_w2, e_b2, e_g2, e_be2,
                                         e_w3, e_b3, IDX);

    // decoder (plain bf16; conv_transpose == conv pad=1, unflipped kernel)
    sconv_k< 7, 7,512,256,1,2,true ,false,1,128,4,2,false><<<B,   256,0,stream>>>(
        nullptr, nullptr, nullptr, nullptr, nullptr, IDX, WB+BKB,
        WB+DW1H, nullptr, d_b1, d_g1, d_be1, nullptr, nullptr, G1, nullptr, nullptr);
    sconv_k< 8, 8,256,128,1,4,true ,false,1, 64,6,2,false><<<B,   256,0,stream>>>(
        nullptr, G1, nullptr, nullptr, nullptr, nullptr, nullptr,
        WB+DW2H, nullptr, d_b2, d_g2, d_be2, nullptr, nullptr, G2, nullptr, nullptr);
    sconv_k< 9, 9,128, 64,1,4,false,false,1, 64,7,0,true ><<<B,   256,0,stream>>>(
        nullptr, G2, ids, masks, table, nullptr, nullptr,
        WB+DW3H, nullptr, d_b3, nullptr, nullptr, out_vqx, nullptr, nullptr, out_mean, ACC);

    loss_k<<<1, 1, 0, stream>>>(ACC, out_loss);
}

// Round 10
// 1221.025 us; speedup vs baseline: 2.0014x; 1.6689x over previous
//
#include <hip/hip_runtime.h>
#include <hip/hip_bf16.h>
#include <cstdint>
#include <cstddef>

// ---------------------------------------------------------------------------
// VQ-VAE forward (B=2048, L=100, D=64, K=64, CB=512) — v5 "fold the codebook".
// conv3 + nn_k replaced by:
//   xnd<true>:  x cols 0..255 (hi-only, for Sum x^2) + dot = A2 (*) W3B
//               (split-bf16) + argmin/margin/qidx/loss2 bookkeeping
//   xnd<false>: x cols 256..511 (Sum x^2 only)
// deconv1 replaced by gather-sum over precomputed BW1[tap][k][oc].
// conv1/conv2/deconv2/deconv3 = round-9 sconv_k (proven). Argmin exactness:
// margin 0.1 flag -> f64 full recompute of flagged rows.
// ---------------------------------------------------------------------------

typedef __attribute__((ext_vector_type(8))) short short8v;   // 8 bf16
typedef __attribute__((ext_vector_type(4))) float f32x4;

constexpr int B  = 2048;
constexpr int L  = 100;
constexpr int K  = 64;
constexpr int CB = 512;
#define MARGIN 0.1f

// ---- workspace layout (float-sized units) ----
constexpr size_t R0_OFF  = 0;          // A1P u32 -> G2 bf16
constexpr size_t R1_OFF  = 51380224;   // A2P u32 -> G1 bf16
constexpr size_t IDX_OFF = 84934656;   // 2048*49 ints
constexpr size_t CBN_OFF = 85035008;   // 64 norms
constexpr size_t CNT_OFF = 85035072;
constexpr size_t ACC_OFF = 85035088;
constexpr size_t WL_OFF  = 85035104;   // 100352 ints
constexpr size_t WB_OFF  = 85135456;   // bf16 weights (ushort units below)

// bf16 weight sub-offsets (ushort units), layout [4][OC][IC]
constexpr size_t EW1H=0,       EW1L=32768;
constexpr size_t EW2H=65536,   EW2L=196608;
constexpr size_t EW3H=327680;                   // [4][512][256] hi only
constexpr size_t DW2H=851968,  DW3H=983040;
constexpr size_t W3BH=1015808, W3BL=1081344;    // [4][64][256] hi/lo
constexpr size_t WB_USH_END=1146880;            // = 573440 floats

constexpr size_t BW1_OFF  = WB_OFF + 573440;    // [4][64][256] f32
constexpr size_t DOTB_OFF = BW1_OFF + 65536;    // 64 f32

__device__ inline ushort bf16_hi(float f){ __hip_bfloat16 h=__float2bfloat16(f); return *(ushort*)&h; }
__device__ inline float  bf16_tof(ushort u){ __hip_bfloat16 h; *(ushort*)&h=u; return __bfloat162float(h); }

// ---------------------------------------------------------------------------
// weight prep: w[2,2,IC,OC] f32 -> Wt[kk][oc][ic] bf16 hi (+lo)
// ---------------------------------------------------------------------------
__device__ void wtrans(const float* __restrict__ w, int IC, int OC,
                       ushort* __restrict__ hi, ushort* __restrict__ lo,
                       int gid, int gsz)
{
    int tot = 4*IC*OC;
    for (int i = gid; i < tot; i += gsz) {
        int kk = i/(IC*OC), r = i - kk*(IC*OC), ic = r/OC, oc = r - ic*OC;
        float v = w[i];
        ushort h = bf16_hi(v);
        size_t dst = ((size_t)kk*OC + oc)*IC + ic;
        hi[dst] = h;
        if (lo) lo[dst] = bf16_hi(v - bf16_tof(h));
    }
}

__global__ __launch_bounds__(256)
void wprep_k(const float* e1, const float* e2, const float* e3,
             const float* d2, const float* d3, ushort* wb)
{
    int gid = blockIdx.x*256 + threadIdx.x, gsz = gridDim.x*256;
    wtrans(e1,  64, 128, wb+EW1H, wb+EW1L, gid, gsz);
    wtrans(e2, 128, 256, wb+EW2H, wb+EW2L, gid, gsz);
    wtrans(e3, 256, 512, wb+EW3H, nullptr, gid, gsz);
    wtrans(d2, 256, 128, wb+DW2H, nullptr, gid, gsz);
    wtrans(d3, 128,  64, wb+DW3H, nullptr, gid, gsz);
}

// ---------------------------------------------------------------------------
// W3B[kk][k][ic] = sum_cb e_w3[kk,ic,cb] * book[k,cb]  (hi/lo bf16)
// block = (kk,k); thread = ic.
// ---------------------------------------------------------------------------
__global__ __launch_bounds__(256)
void w3b_k(const float* __restrict__ e_w3, const float* __restrict__ book,
           ushort* __restrict__ wb)
{
    const int kk = blockIdx.x >> 6, k = blockIdx.x & 63, ic = threadIdx.x;
    const float4* wr = (const float4*)(e_w3 + ((size_t)(kk*256)+ic)*512);
    const float4* br = (const float4*)(book + (size_t)k*512);
    float s = 0.f;
    for (int c = 0; c < 128; ++c) {
        float4 a = wr[c], bb = br[c];
        s = fmaf(a.x,bb.x,fmaf(a.y,bb.y,fmaf(a.z,bb.z,fmaf(a.w,bb.w,s))));
    }
    size_t dst = ((size_t)(kk*64+k))*256 + ic;
    ushort h = bf16_hi(s);
    wb[W3BH+dst] = h;
    wb[W3BL+dst] = bf16_hi(s - bf16_tof(h));
}

// ---------------------------------------------------------------------------
// BW1[tap][k][oc] = sum_ic book[k,ic] * d_w1[tap,ic,oc]   (f32)
// block = (tap,k); thread = oc.
// ---------------------------------------------------------------------------
__global__ __launch_bounds__(256)
void bw1_k(const float* __restrict__ d_w1, const float* __restrict__ book,
           float* __restrict__ bw1)
{
    const int tap = blockIdx.x >> 6, k = blockIdx.x & 63, oc = threadIdx.x;
    const float* br = book + (size_t)k*512;
    const float* wr = d_w1 + (size_t)(tap*512)*256 + oc;
    float s = 0.f;
    for (int ic = 0; ic < 512; ++ic)
        s = fmaf(br[ic], wr[(size_t)ic*256], s);
    bw1[((size_t)(tap*64+k))*256 + oc] = s;
}

// ---------------------------------------------------------------------------
// prep: code norms, dotbias, zero accumulators + worklist count
// ---------------------------------------------------------------------------
__global__ __launch_bounds__(256)
void prep_k(const float* __restrict__ book, const float* __restrict__ e_b3,
            float* __restrict__ cbn, float* __restrict__ dotb,
            float* __restrict__ acc, int* __restrict__ cnt)
{
    const int t = threadIdx.x;
    if (t < 64) {
        const float* r = book + t * 512;
        float s = 0.f, d = 0.f;
        for (int c = 0; c < 512; ++c) { s = fmaf(r[c], r[c], s); d = fmaf(e_b3[c], r[c], d); }
        cbn[t] = s; dotb[t] = d;
    }
    if (t == 64 || t == 65) acc[t-64] = 0.f;
    if (t == 66) *cnt = 0;
}

// ---------------------------------------------------------------------------
// Per-sample MFMA conv (round-9, proven). Block = (sample b, oc-slice sl),
// XCD-remapped. LDS double-buffered, one barrier per chunk, T14 prefetch,
// setprio around MFMA cluster.
// MODE 1: table gather+mask; 3: packed u32 hi|lo; 4: bf16.
// OUTFMT 0: f32; 1: packed u32; 2: bf16.  FUSE: vq_mean + loss1 epilogue.
// ---------------------------------------------------------------------------
template<int IH,int IW,int IC,int OC,int PAD,int MODE,bool HASBN,bool SPLIT,
         int OCS,int ICC,int MT,int OUTFMT,bool FUSE>
__global__ __launch_bounds__(256)
void sconv_k(const uint* __restrict__ in_pk, const ushort* __restrict__ in_bf,
             const int* __restrict__ ids, const int* __restrict__ masks,
             const float* __restrict__ table,
             const ushort* __restrict__ wt_hi, const ushort* __restrict__ wt_lo,
             const float* __restrict__ bias, const float* __restrict__ gamma,
             const float* __restrict__ beta,
             float* __restrict__ out_f, uint* __restrict__ out_pk,
             ushort* __restrict__ out_bf, float* __restrict__ out_mean,
             float* __restrict__ acc_g)
{
    constexpr int OH=IH+2*PAD-1, OW=IW+2*PAD-1, NPOS=OH*OW, IHW=IH*IW;
    constexpr int OCB=OC/OCS, NPW=OCB/4, NT=NPW/16;
    constexpr int NCH=IC/ICC, KS=ICC/32;
    constexpr int PL=SPLIT?2:1;
    constexpr int NB=(NCH>1)?2:1;
    constexpr int AROWS=IHW+1, RB=ICC*2;
    constexpr int C8=ICC/8;
    constexpr int NITEMS=IHW*C8;
    constexpr int SI=(NITEMS+255)/256;
    constexpr bool EXACT=(SI*256==NITEMS);
    constexpr int BUFB=PL*AROWS*RB;

    __shared__ ushort s_a[NB*PL*AROWS*ICC];
    char* sb=(char*)s_a;

    const int v=blockIdx.x, r8=v&7, iv=v>>3;
    const int b = r8*(B/8) + iv/OCS;
    const int sl = iv - (iv/OCS)*OCS;

    const int tid=threadIdx.x, lane=tid&63, wv=tid>>6;
    const int l15=lane&15, lq=lane>>4;
    const int n0=sl*OCB + wv*NPW;

    int arow[4][MT];
    #pragma unroll
    for(int kk=0;kk<4;++kk){
        const int ky=kk>>1, kx=kk&1;
        #pragma unroll
        for(int m=0;m<MT;++m){
            int p=m*16+l15;
            int py=p/OW, px=p-py*OW;
            int ty=py+ky-PAD, tx=px+kx-PAD;
            bool ok=(p<NPOS)&&((unsigned)ty<(unsigned)IH)&&((unsigned)tx<(unsigned)IW);
            arow[kk][m]= ok ? ty*IW+tx : IHW;
        }
    }

    f32x4 acc[MT][NT];
    #pragma unroll
    for(int m=0;m<MT;++m)
        #pragma unroll
        for(int n=0;n<NT;++n) acc[m][n]=(f32x4)0.0f;

    uint4 r0[SI];
    uint4 r1[(MODE==1||MODE==3)?SI:1];
    float msk[(MODE==1)?SI:1];

    auto stage_load=[&](int c){
        const int ic0=c*ICC;
        #pragma unroll
        for(int t=0;t<SI;++t){
            int idx=tid+t*256;
            if(EXACT || idx<NITEMS){
                int row=idx/C8, g=idx-row*C8;
                if constexpr(MODE==1){
                    int id=ids[b*L+row];
                    msk[t]=(masks[b*L+row]>=1)?1.f:0.f;
                    const float* src=table+(size_t)id*64+g*8;
                    r0[t]=*(const uint4*)src;
                    r1[t]=*(const uint4*)(src+4);
                } else if constexpr(MODE==3){
                    const uint* src=in_pk+((size_t)b*IHW+row)*IC+ic0+g*8;
                    r0[t]=*(const uint4*)src;
                    r1[t]=*(const uint4*)(src+4);
                } else {
                    r0[t]=*(const uint4*)(in_bf+((size_t)b*IHW+row)*IC+ic0+g*8);
                }
            }
        }
    };

    auto stage_write=[&](int bufb){
        #pragma unroll
        for(int t=0;t<SI;++t){
            int idx=tid+t*256;
            if(EXACT || idx<NITEMS){
                int row=idx/C8, g=idx-row*C8;
                int boff=bufb + row*RB + ((g^(row&7))<<4);
                if constexpr(MODE==1){
                    const float* f0=(const float*)&r0[t];
                    const float* f1=(const float*)&r1[t];
                    float vv[8]={f0[0]*msk[t],f0[1]*msk[t],f0[2]*msk[t],f0[3]*msk[t],
                                 f1[0]*msk[t],f1[1]*msk[t],f1[2]*msk[t],f1[3]*msk[t]};
                    ushort hh[8], ll[8];
                    #pragma unroll
                    for(int j=0;j<8;++j){ hh[j]=bf16_hi(vv[j]); ll[j]=bf16_hi(vv[j]-bf16_tof(hh[j])); }
                    *(uint4*)(sb+boff)=*(uint4*)hh;
                    *(uint4*)(sb+AROWS*RB+boff)=*(uint4*)ll;
                } else if constexpr(MODE==3){
                    const uint* u0=(const uint*)&r0[t];
                    const uint* u1=(const uint*)&r1[t];
                    ushort hh[8], ll[8];
                    #pragma unroll
                    for(int j=0;j<4;++j){ hh[j]=(ushort)(u0[j]&0xffffu); ll[j]=(ushort)(u0[j]>>16); }
                    #pragma unroll
                    for(int j=0;j<4;++j){ hh[4+j]=(ushort)(u1[j]&0xffffu); ll[4+j]=(ushort)(u1[j]>>16); }
                    *(uint4*)(sb+boff)=*(uint4*)hh;
                    *(uint4*)(sb+AROWS*RB+boff)=*(uint4*)ll;
                } else {
                    *(uint4*)(sb+boff)=r0[t];
                }
            }
        }
    };

    stage_load(0);
    stage_write(0);
    for(int z=tid; z<NB*PL*C8; z+=256){
        int nb=z/(PL*C8), rz=z-nb*(PL*C8), pl=rz/C8, g=rz-pl*C8;
        *(uint4*)(sb + nb*BUFB + pl*(AROWS*RB) + IHW*RB + (g<<4)) = make_uint4(0,0,0,0);
    }
    __syncthreads();

    for(int c=0;c<NCH;++c){
        if(c+1<NCH) stage_load(c+1);
        const int bufb=(c&1)*BUFB;
        const int ic0=c*ICC;
        __builtin_amdgcn_s_setprio(1);
        #pragma unroll
        for(int kk=0;kk<4;++kk){
            #pragma unroll
            for(int ks=0;ks<KS;++ks){
                short8v bhv[NT]; short8v blv[SPLIT?NT:1];
                #pragma unroll
                for(int n=0;n<NT;++n){
                    int col=n0+n*16+l15;
                    size_t widx=((size_t)kk*OC+col)*IC+ic0+ks*32+lq*8;
                    bhv[n]=*(const short8v*)(wt_hi+widx);
                    if constexpr(SPLIT) blv[n]=*(const short8v*)(wt_lo+widx);
                }
                #pragma unroll
                for(int m=0;m<MT;++m){
                    int off=bufb + arow[kk][m]*RB + ((((ks<<2)|lq)^(arow[kk][m]&7))<<4);
                    short8v ah=*(const short8v*)(sb+off);
                    if constexpr(SPLIT){
                        short8v al=*(const short8v*)(sb+AROWS*RB+off);
                        #pragma unroll
                        for(int n=0;n<NT;++n){
                            acc[m][n]=__builtin_amdgcn_mfma_f32_16x16x32_bf16(ah,bhv[n],acc[m][n],0,0,0);
                            acc[m][n]=__builtin_amdgcn_mfma_f32_16x16x32_bf16(ah,blv[n],acc[m][n],0,0,0);
                            acc[m][n]=__builtin_amdgcn_mfma_f32_16x16x32_bf16(al,bhv[n],acc[m][n],0,0,0);
                        }
                    } else {
                        #pragma unroll
                        for(int n=0;n<NT;++n)
                            acc[m][n]=__builtin_amdgcn_mfma_f32_16x16x32_bf16(ah,bhv[n],acc[m][n],0,0,0);
                    }
                }
            }
        }
        __builtin_amdgcn_s_setprio(0);
        if(c+1<NCH){
            stage_write(((c+1)&1)*BUFB);
            __syncthreads();
        }
    }

    const float rs=(float)(1.0/sqrt(1.0+1e-3));
    float lsum=0.f, colsum=0.f;
    #pragma unroll
    for(int n=0;n<NT;++n){
        int col=n0+n*16+l15;
        float bi=bias[col];
        float gsc=0.f, bt=0.f;
        if constexpr(HASBN){ gsc=gamma[col]*rs; bt=beta[col]; }
        #pragma unroll
        for(int m=0;m<MT;++m){
            #pragma unroll
            for(int j=0;j<4;++j){
                int p=m*16+lq*4+j;
                if(p<NPOS){
                    float vx=acc[m][n][j]+bi;
                    if constexpr(HASBN) vx=fmaxf(fmaf(vx,gsc,bt),0.f);
                    size_t g=(size_t)b*NPOS+p;
                    if constexpr(OUTFMT==0){
                        out_f[g*OC+col]=vx;
                    } else if constexpr(OUTFMT==1){
                        ushort h=bf16_hi(vx);
                        ushort lo=bf16_hi(vx-bf16_tof(h));
                        out_pk[g*OC+col]=(uint)h | ((uint)lo<<16);
                    } else {
                        out_bf[g*OC+col]=bf16_hi(vx);
                    }
                    if constexpr(FUSE){
                        int id=ids[b*L+p];
                        float mm=(masks[b*L+p]>=1)?1.f:0.f;
                        float h=table[(size_t)id*64+col]*mm;
                        float df=h-vx;
                        lsum=fmaf(df,df,lsum);
                        colsum+=vx;
                    }
                }
            }
        }
    }

    if constexpr(FUSE){
        float mc=0.f;
        for(int l=lane;l<L;l+=64) mc += (masks[b*L+l]>=1)?1.f:0.f;
        #pragma unroll
        for(int off=32;off;off>>=1) mc+=__shfl_xor(mc,off);
        colsum += __shfl_xor(colsum,16);
        colsum += __shfl_xor(colsum,32);
        if(lq==0) out_mean[b*64 + n0 + l15] = colsum/mc;
        #pragma unroll
        for(int off=32;off;off>>=1) lsum+=__shfl_xor(lsum,off);
        __syncthreads();
        float* red=(float*)sb;
        if(lane==0) red[wv]=lsum;
        __syncthreads();
        if(tid==0) atomicAdd(acc_g+0, red[0]+red[1]+red[2]+red[3]);
    }
}

// ---------------------------------------------------------------------------
// xnd: x-columns (Sum x^2, no store) and (DOT) folded codebook dots + argmin.
// Input A2P packed u32 [B,64,256]. Block = sample (XCD-remapped), 4 waves.
// DOT=true : x cols 0..255 (NT=4, hi-only) + dot (NT=1, split 3-MFMA) +
//            per-row argmin/margin/qidx + Sum dmin -> ACC[1].
// DOT=false: x cols 256..511 only.  Both add Sum x^2 -> ACC[1].
// ---------------------------------------------------------------------------
template<bool DOT>
__global__ __launch_bounds__(256)
void xnd_k(const uint* __restrict__ in_pk,
           const ushort* __restrict__ wx,                       // EW3H
           const ushort* __restrict__ w3bh, const ushort* __restrict__ w3bl,
           const float* __restrict__ xbias,                     // e_b3
           const float* __restrict__ cbn, const float* __restrict__ dotb,
           int* __restrict__ qidx, float* __restrict__ acc_g,
           int* __restrict__ cnt, int* __restrict__ wl)
{
    constexpr int IHW=64, AROWS=65, RB=128, NCH=4, C8=8;
    constexpr int NPOS=49, OW=7, MT=4, NT=4;
    constexpr int PLX=DOT?2:1;
    constexpr int BUFB=PLX*AROWS*RB;

    __shared__ ushort s_a[2*PLX*AROWS*64];
    char* sb=(char*)s_a;

    const int v=blockIdx.x;
    const int b=(v&7)*(B/8)+(v>>3);
    const int tid=threadIdx.x, lane=tid&63, wv=tid>>6;
    const int l15=lane&15, lq=lane>>4;
    const int n0x=(DOT?0:256)+wv*64;

    int arow[4][MT];
    #pragma unroll
    for(int kk=0;kk<4;++kk){
        const int ky=kk>>1, kx=kk&1;
        #pragma unroll
        for(int m=0;m<MT;++m){
            int p=m*16+l15;
            int py=p/OW, px=p-py*OW;
            bool ok=(p<NPOS);
            arow[kk][m]= ok ? (py+ky)*8+(px+kx) : IHW;
        }
    }

    f32x4 accx[MT][NT];
    #pragma unroll
    for(int m=0;m<MT;++m)
        #pragma unroll
        for(int n=0;n<NT;++n) accx[m][n]=(f32x4)0.0f;
    f32x4 accd[DOT?MT:1];
    #pragma unroll
    for(int m=0;m<(DOT?MT:1);++m) accd[m]=(f32x4)0.0f;

    uint4 r0[2], r1[2];

    auto stage_load=[&](int c){
        const int ic0=c*64;
        #pragma unroll
        for(int t=0;t<2;++t){
            int idx=tid+t*256;
            int row=idx>>3, g=idx&7;
            const uint* src=in_pk+((size_t)b*IHW+row)*256+ic0+g*8;
            r0[t]=*(const uint4*)src;
            r1[t]=*(const uint4*)(src+4);
        }
    };
    auto stage_write=[&](int bufb){
        #pragma unroll
        for(int t=0;t<2;++t){
            int idx=tid+t*256;
            int row=idx>>3, g=idx&7;
            int boff=bufb + row*RB + ((g^(row&7))<<4);
            const uint* u0=(const uint*)&r0[t];
            const uint* u1=(const uint*)&r1[t];
            ushort hh[8];
            #pragma unroll
            for(int j=0;j<4;++j){ hh[j]=(ushort)(u0[j]&0xffffu); hh[4+j]=(ushort)(u1[j]&0xffffu); }
            *(uint4*)(sb+boff)=*(uint4*)hh;
            if constexpr(DOT){
                ushort ll[8];
                #pragma unroll
                for(int j=0;j<4;++j){ ll[j]=(ushort)(u0[j]>>16); ll[4+j]=(ushort)(u1[j]>>16); }
                *(uint4*)(sb+AROWS*RB+boff)=*(uint4*)ll;
            }
        }
    };

    stage_load(0);
    stage_write(0);
    for(int z=tid; z<2*PLX*C8; z+=256){
        int nb=z/(PLX*C8), rz=z-nb*(PLX*C8), pl=rz/C8, g=rz-pl*C8;
        *(uint4*)(sb + nb*BUFB + pl*(AROWS*RB) + IHW*RB + (g<<4)) = make_uint4(0,0,0,0);
    }
    __syncthreads();

    for(int c=0;c<NCH;++c){
        if(c+1<NCH) stage_load(c+1);
        const int bufb=(c&1)*BUFB;
        const int ic0=c*64;
        __builtin_amdgcn_s_setprio(1);
        #pragma unroll
        for(int kk=0;kk<4;++kk){
            #pragma unroll
            for(int ks=0;ks<2;++ks){
                short8v bx[NT];
                #pragma unroll
                for(int n=0;n<NT;++n){
                    int col=n0x+n*16+l15;
                    bx[n]=*(const short8v*)(wx+((size_t)kk*512+col)*256+ic0+ks*32+lq*8);
                }
                short8v bdh, bdl;
                if constexpr(DOT){
                    int cold=wv*16+l15;
                    size_t wdx=((size_t)kk*64+cold)*256+ic0+ks*32+lq*8;
                    bdh=*(const short8v*)(w3bh+wdx);
                    bdl=*(const short8v*)(w3bl+wdx);
                }
                #pragma unroll
                for(int m=0;m<MT;++m){
                    int off=bufb + arow[kk][m]*RB + ((((ks<<2)|lq)^(arow[kk][m]&7))<<4);
                    short8v ah=*(const short8v*)(sb+off);
                    #pragma unroll
                    for(int n=0;n<NT;++n)
                        accx[m][n]=__builtin_amdgcn_mfma_f32_16x16x32_bf16(ah,bx[n],accx[m][n],0,0,0);
                    if constexpr(DOT){
                        short8v al=*(const short8v*)(sb+AROWS*RB+off);
                        accd[m]=__builtin_amdgcn_mfma_f32_16x16x32_bf16(ah,bdh,accd[m],0,0,0);
                        accd[m]=__builtin_amdgcn_mfma_f32_16x16x32_bf16(ah,bdl,accd[m],0,0,0);
                        accd[m]=__builtin_amdgcn_mfma_f32_16x16x32_bf16(al,bdh,accd[m],0,0,0);
                    }
                }
            }
        }
        __builtin_amdgcn_s_setprio(0);
        if(c+1<NCH){
            stage_write(((c+1)&1)*BUFB);
            __syncthreads();
        }
    }

    // Sum x^2 over this block's columns
    float xs=0.f;
    #pragma unroll
    for(int n=0;n<NT;++n){
        int col=n0x+n*16+l15;
        float bi=xbias[col];
        #pragma unroll
        for(int m=0;m<MT;++m){
            #pragma unroll
            for(int j=0;j<4;++j){
                int p=m*16+lq*4+j;
                if(p<NPOS){ float vv=accx[m][n][j]+bi; xs=fmaf(vv,vv,xs); }
            }
        }
    }
    #pragma unroll
    for(int off=32;off;off>>=1) xs+=__shfl_xor(xs,off);
    __syncthreads();                        // LDS reuse safe
    float* f=(float*)sb;
    if(lane==0) f[wv]=xs;

    if constexpr(DOT){
        float cb=cbn[wv*16+l15], db=dotb[wv*16+l15];
        float* sd1=f+8;
        int*   sk =(int*)(f+8+256);
        float* sd2=f+8+512;
        #pragma unroll
        for(int m=0;m<MT;++m){
            #pragma unroll
            for(int j=0;j<4;++j){
                int p=m*16+lq*4+j;
                float d1=cb-2.f*(accd[m][j]+db);
                int   k1=wv*16+l15;
                float d2=3.4e38f;
                #pragma unroll
                for(int off=1;off<16;off<<=1){
                    float od1=__shfl_xor(d1,off);
                    int   ok1=__shfl_xor(k1,off);
                    float od2=__shfl_xor(d2,off);
                    if(od1<d1 || (od1==d1 && ok1<k1)){ d2=fminf(d1,od2); d1=od1; k1=ok1; }
                    else                              { d2=fminf(d2,od1); }
                }
                if(l15==0){ sd1[p*4+wv]=d1; sk[p*4+wv]=k1; sd2[p*4+wv]=d2; }
            }
        }
    }
    __syncthreads();
    if(tid==0) atomicAdd(acc_g+1, f[0]+f[1]+f[2]+f[3]);

    if constexpr(DOT){
        float* sd1=f+8;
        int*   sk =(int*)(f+8+256);
        float* sd2=f+8+512;
        float lsum=0.f;
        if(tid<NPOS){
            float d1=sd1[tid*4+0]; int k1=sk[tid*4+0]; float d2=sd2[tid*4+0];
            #pragma unroll
            for(int w=1;w<4;++w){
                float D1=sd1[tid*4+w]; int K1=sk[tid*4+w]; float D2=sd2[tid*4+w];
                if(D1<d1){ d2=fminf(d1,D2); d1=D1; k1=K1; }
                else     { d2=fminf(d2,D1); }
            }
            qidx[b*49+tid]=k1;
            if(d2-d1<=MARGIN){ int t=atomicAdd(cnt,1); wl[t]=b*49+tid; }
            lsum=d1;
        }
        if(tid<64){
            #pragma unroll
            for(int off=32;off;off>>=1) lsum+=__shfl_xor(lsum,off);
            if(lane==0) atomicAdd(acc_g+1, lsum);
        }
    }
}

// ---------------------------------------------------------------------------
// deconv1 as gather-sum over BW1: g[b,p,oc] = sum_valid_taps BW1[tap][idx][oc]
// then bias+BN+relu -> G1 bf16. Block = sample; thread = (pos, oc-group).
// ---------------------------------------------------------------------------
__global__ __launch_bounds__(256)
void dgather_k(const int* __restrict__ qidx, const float* __restrict__ bw1,
               const float* __restrict__ b1, const float* __restrict__ g1s,
               const float* __restrict__ be1, ushort* __restrict__ G1)
{
    const int b=blockIdx.x, tid=threadIdx.x;
    const int pg=tid>>2, og=(tid&3)*64;
    const int py=pg>>3, px=pg&7;

    float a[64];
    #pragma unroll
    for(int j=0;j<64;++j) a[j]=0.f;

    #pragma unroll
    for(int tap=0;tap<4;++tap){
        int iy=py+(tap>>1)-1, ix=px+(tap&1)-1;
        if((unsigned)iy<7u && (unsigned)ix<7u){
            int kq=qidx[b*49+iy*7+ix];
            const float4* src=(const float4*)(bw1+((size_t)(tap*64+kq))*256+og);
            #pragma unroll
            for(int j=0;j<16;++j){
                float4 vv=src[j];
                a[4*j+0]+=vv.x; a[4*j+1]+=vv.y; a[4*j+2]+=vv.z; a[4*j+3]+=vv.w;
            }
        }
    }
    const float rs=(float)(1.0/sqrt(1.0+1e-3));
    #pragma unroll
    for(int j=0;j<64;++j){
        int col=og+j;
        float vv=a[j]+b1[col];
        vv=fmaxf(fmaf(vv, g1s[col]*rs, be1[col]), 0.f);
        G1[((size_t)b*64+pg)*256+col]=bf16_hi(vv);
    }
}

// ---------------------------------------------------------------------------
// f64 re-verification of flagged rows (full receptive field from scratch).
// ---------------------------------------------------------------------------
__global__ __launch_bounds__(256)
void recompute_k(const int* __restrict__ wl, const int* __restrict__ cnt,
                 const int* __restrict__ ids, const int* __restrict__ masks,
                 const float* __restrict__ table, const float* __restrict__ book,
                 const float* __restrict__ e_w1, const float* __restrict__ e_b1,
                 const float* __restrict__ e_g1, const float* __restrict__ e_be1,
                 const float* __restrict__ e_w2, const float* __restrict__ e_b2,
                 const float* __restrict__ e_g2, const float* __restrict__ e_be2,
                 const float* __restrict__ e_w3, const float* __restrict__ e_b3,
                 int* __restrict__ qidx)
{
    __shared__ double s_h[16*64];
    __shared__ double s_a1[9*128];
    __shared__ double s_a2[4*256];
    __shared__ double s_x[512];
    __shared__ double s_d[256];

    const int tid = threadIdx.x;
    const double rs = 1.0 / sqrt(1.0 + 1e-3);
    const int n = *cnt;

    for (int wi = blockIdx.x; wi < n; wi += gridDim.x) {
        const int row = wl[wi];
        const int b = row / 49, p = row % 49;
        const int py = p / 7, px = p % 7;

        for (int i = tid; i < 16*64; i += 256) {
            int cell = i >> 6, d = i & 63;
            int l = (py + (cell >> 2)) * 10 + (px + (cell & 3));
            int id = ids[b*100 + l];
            double m = (masks[b*100 + l] >= 1) ? 1.0 : 0.0;
            s_h[i] = (double)table[(size_t)id*64 + d] * m;
        }
        __syncthreads();

        for (int i = tid; i < 9*128; i += 256) {
            int cell = i >> 7, oc = i & 127;
            int ry = cell / 3, rx = cell % 3;
            double s = 0.0;
            #pragma unroll
            for (int kk = 0; kk < 4; ++kk) {
                int icell = (ry + (kk>>1))*4 + (rx + (kk&1));
                const double* hh = s_h + icell*64;
                const float* ww = e_w1 + (kk*64)*128 + oc;
                for (int ic = 0; ic < 64; ++ic)
                    s = fma(hh[ic], (double)ww[ic*128], s);
            }
            s += (double)e_b1[oc];
            s = s * ((double)e_g1[oc] * rs) + (double)e_be1[oc];
            s_a1[i] = s > 0.0 ? s : 0.0;
        }
        __syncthreads();

        for (int i = tid; i < 4*256; i += 256) {
            int cell = i >> 8, oc = i & 255;
            int qy = cell >> 1, qx = cell & 1;
            double s = 0.0;
            #pragma unroll
            for (int kk = 0; kk < 4; ++kk) {
                int icell = (qy + (kk>>1))*3 + (qx + (kk&1));
                const double* aa = s_a1 + icell*128;
                const float* ww = e_w2 + (kk*128)*256 + oc;
                for (int ic = 0; ic < 128; ++ic)
                    s = fma(aa[ic], (double)ww[ic*256], s);
            }
            s += (double)e_b2[oc];
            s = s * ((double)e_g2[oc] * rs) + (double)e_be2[oc];
            s_a2[i] = s > 0.0 ? s : 0.0;
        }
        __syncthreads();

        for (int i = tid; i < 512; i += 256) {
            double s = 0.0;
            #pragma unroll
            for (int kk = 0; kk < 4; ++kk) {
                const double* aa = s_a2 + kk*256;
                const float* ww = e_w3 + (kk*256)*512 + i;
                for (int ic = 0; ic < 256; ++ic)
                    s = fma(aa[ic], (double)ww[ic*512], s);
            }
            s_x[i] = s + (double)e_b3[i];
        }
        __syncthreads();

        {
            int k = tid & 63, seg = tid >> 6;
            const float* cr = book + k*512 + seg*128;
            const double* xr = s_x + seg*128;
            double s = 0.0;
            for (int c = 0; c < 128; ++c) {
                double dd = xr[c] - (double)cr[c];
                s = fma(dd, dd, s);
            }
            s_d[seg*64 + k] = s;
        }
        __syncthreads();

        if (tid < 64) {
            double dv = s_d[tid] + s_d[64+tid] + s_d[128+tid] + s_d[192+tid];
            int kk2 = tid;
            #pragma unroll
            for (int off = 32; off > 0; off >>= 1) {
                double od = __shfl_xor(dv, off);
                int    ok = __shfl_xor(kk2, off);
                if (od < dv || (od == dv && ok < kk2)) { dv = od; kk2 = ok; }
            }
            if (tid == 0) qidx[row] = kk2;
        }
        __syncthreads();
    }
}

__global__ void loss_k(const float* __restrict__ acc, float* __restrict__ out_loss)
{
    float l1 = acc[0] / 13107200.f;
    float l2 = acc[1] / 51380224.f;
    out_loss[0] = l1 + l2 + 0.25f * l2;
}

// ---------------------------------------------------------------------------
extern "C" void kernel_launch(void* const* d_in, const int* in_sizes, int n_in,
                              void* d_out, int out_size, void* d_ws, size_t ws_size,
                              hipStream_t stream)
{
    const int*   ids   = (const int*)d_in[0];
    const int*   masks = (const int*)d_in[1];
    const float* table = (const float*)d_in[2];
    const float* book  = (const float*)d_in[3];
    const float* e_w1  = (const float*)d_in[4];
    const float* e_b1  = (const float*)d_in[5];
    const float* e_g1  = (const float*)d_in[6];
    const float* e_be1 = (const float*)d_in[7];
    const float* e_w2  = (const float*)d_in[8];
    const float* e_b2  = (const float*)d_in[9];
    const float* e_g2  = (const float*)d_in[10];
    const float* e_be2 = (const float*)d_in[11];
    const float* e_w3  = (const float*)d_in[12];
    const float* e_b3  = (const float*)d_in[13];
    const float* d_w1  = (const float*)d_in[14];
    const float* d_b1  = (const float*)d_in[15];
    const float* d_g1  = (const float*)d_in[16];
    const float* d_be1 = (const float*)d_in[17];
    const float* d_w2  = (const float*)d_in[18];
    const float* d_b2  = (const float*)d_in[19];
    const float* d_g2  = (const float*)d_in[20];
    const float* d_be2 = (const float*)d_in[21];
    const float* d_w3  = (const float*)d_in[22];
    const float* d_b3  = (const float*)d_in[23];

    float*  ws  = (float*)d_ws;
    uint*   A1P = (uint*)(ws + R0_OFF);   // [B*81*128] u32 hi|lo
    uint*   A2P = (uint*)(ws + R1_OFF);   // [B*64*256] u32 hi|lo
    ushort* G1  = (ushort*)(ws + R1_OFF); // [B*64*256] bf16 (after xnd)
    ushort* G2  = (ushort*)(ws + R0_OFF); // [B*81*128] bf16 (after conv2)
    int*    IDX = (int*)(ws + IDX_OFF);
    float*  CBN = ws + CBN_OFF;
    int*    CNT = (int*)(ws + CNT_OFF);
    float*  ACC = ws + ACC_OFF;
    int*    WL  = (int*)(ws + WL_OFF);
    ushort* WB  = (ushort*)(ws + WB_OFF);
    float*  BW1 = ws + BW1_OFF;
    float*  DOTB= ws + DOTB_OFF;

    float* out_mean = (float*)d_out;
    float* out_vqx  = (float*)d_out + (size_t)B * 64;
    float* out_loss = (float*)d_out + (size_t)B * 64 + (size_t)B * L * 64;

    prep_k<<<1, 256, 0, stream>>>(book, e_b3, CBN, DOTB, ACC, CNT);
    wprep_k<<<512, 256, 0, stream>>>(e_w1, e_w2, e_w3, d_w2, d_w3, WB);
    w3b_k<<<256, 256, 0, stream>>>(e_w3, book, WB);
    bw1_k<<<256, 256, 0, stream>>>(d_w1, book, BW1);

    // encoder (split-bf16)
    sconv_k<10,10, 64,128,0,1,true ,true ,1, 64,6,1,false><<<B,   256,0,stream>>>(
        nullptr, nullptr, ids, masks, table,
        WB+EW1H, WB+EW1L, e_b1, e_g1, e_be1, nullptr, A1P, nullptr, nullptr, nullptr);
    sconv_k< 9, 9,128,256,0,3,true ,true ,2, 64,4,1,false><<<B*2, 256,0,stream>>>(
        A1P, nullptr, nullptr, nullptr, nullptr,
        WB+EW2H, WB+EW2L, e_b2, e_g2, e_be2, nullptr, A2P, nullptr, nullptr, nullptr);

    // x^2 + folded-codebook dots + argmin (replaces conv3 + nn_k)
    xnd_k<true ><<<B, 256, 0, stream>>>(A2P, WB+EW3H, WB+W3BH, WB+W3BL,
                                        e_b3, CBN, DOTB, IDX, ACC, CNT, WL);
    xnd_k<false><<<B, 256, 0, stream>>>(A2P, WB+EW3H, nullptr, nullptr,
                                        e_b3, nullptr, nullptr, nullptr, ACC, nullptr, nullptr);

    // f64 re-verify flagged rows
    recompute_k<<<512, 256, 0, stream>>>(WL, CNT, ids, masks, table, book,
                                         e_w1, e_b1, e_g1, e_be1,
                                         e_w2, e_b2, e_g2, e_be2,
                                         e_w3, e_b3, IDX);

    // decoder: deconv1 = gather-sum; deconv2/3 = bf16 MFMA convs
    dgather_k<<<B, 256, 0, stream>>>(IDX, BW1, d_b1, d_g1, d_be1, G1);
    sconv_k< 8, 8,256,128,1,4,true ,false,1, 64,6,2,false><<<B,   256,0,stream>>>(
        nullptr, G1, nullptr, nullptr, nullptr,
        WB+DW2H, nullptr, d_b2, d_g2, d_be2, nullptr, nullptr, G2, nullptr, nullptr);
    sconv_k< 9, 9,128, 64,1,4,false,false,1, 64,7,0,true ><<<B,   256,0,stream>>>(
        nullptr, G2, ids, masks, table,
        WB+DW3H, nullptr, d_b3, nullptr, nullptr, out_vqx, nullptr, nullptr, out_mean, ACC);

    loss_k<<<1, 1, 0, stream>>>(ACC, out_loss);
}